// Round 5
// baseline (1900.912 us; speedup 1.0000x reference)
//
#include <hip/hip_runtime.h>

#define NN   100000
#define NE   1600000
#define NB   400000     // NN*4 (dst,rel) segments
#define EPS  1e-10f

#define NBLK_SCAN 391   // ceil(NB/1024)

typedef __attribute__((ext_vector_type(8))) short bfrag8;
typedef __attribute__((ext_vector_type(4))) float f4acc;

__device__ __forceinline__ unsigned short f2bf(float f) {
    union { float f; unsigned u; } v; v.f = f;
    unsigned r = v.u + 0x7FFF + ((v.u >> 16) & 1);
    return (unsigned short)(r >> 16);
}
__device__ __forceinline__ float bf2f(unsigned short b) {
    union { unsigned u; float f; } v; v.u = ((unsigned)b) << 16;
    return v.f;
}

// ---------------------------------------------------------------------------
// CSR build: key = dst*4 + rel  (400K segments)
// ---------------------------------------------------------------------------
__global__ __launch_bounds__(256) void k_hist(
    const int* __restrict__ dst, const int* __restrict__ rel,
    int* __restrict__ cnt)
{
    int stride = gridDim.x * blockDim.x;
    for (int e = blockIdx.x * blockDim.x + threadIdx.x; e < NE; e += stride)
        atomicAdd(&cnt[dst[e] * 4 + rel[e]], 1);
}

__global__ __launch_bounds__(1024) void k_scan_local(
    const int* __restrict__ cnt, int* __restrict__ row_ptr,
    int* __restrict__ blksum)
{
    __shared__ int s[1024];
    int t = threadIdx.x;
    int i = blockIdx.x * 1024 + t;
    int v = (i < NB) ? cnt[i] : 0;
    s[t] = v;
    __syncthreads();
    #pragma unroll
    for (int off = 1; off < 1024; off <<= 1) {
        int u = (t >= off) ? s[t - off] : 0;
        __syncthreads();
        s[t] += u;
        __syncthreads();
    }
    if (i < NB) row_ptr[i] = s[t] - v;
    if (t == 1023) blksum[blockIdx.x] = s[t];
}

__global__ __launch_bounds__(512) void k_scan_blk(
    int* __restrict__ blksum, int* __restrict__ blkoff, int* __restrict__ row_ptr)
{
    __shared__ int s[512];
    int t = threadIdx.x;
    int v = (t < NBLK_SCAN) ? blksum[t] : 0;
    s[t] = v;
    __syncthreads();
    #pragma unroll
    for (int off = 1; off < 512; off <<= 1) {
        int u = (t >= off) ? s[t - off] : 0;
        __syncthreads();
        s[t] += u;
        __syncthreads();
    }
    if (t < NBLK_SCAN) blkoff[t] = s[t] - v;
    if (t == NBLK_SCAN - 1) row_ptr[NB] = s[t];
}

__global__ __launch_bounds__(1024) void k_scan_add(
    int* __restrict__ row_ptr, const int* __restrict__ blkoff,
    int* __restrict__ cursor)
{
    int i = blockIdx.x * 1024 + threadIdx.x;
    if (i < NB) {
        int v = row_ptr[i] + blkoff[blockIdx.x];
        row_ptr[i] = v;
        cursor[i] = v;
    }
}

// reorder: pack (src | local_bucket<<20), where local_bucket=(dst%16)*4+rel.
// Also write 4 pad entries (src=0, w=0) at edat[NE..NE+3].
__global__ __launch_bounds__(256) void k_reorder(
    const int* __restrict__ src, const int* __restrict__ dst,
    const int* __restrict__ rel, const float* __restrict__ ew,
    int* __restrict__ cursor, int2* __restrict__ edat)
{
    int g = blockIdx.x * blockDim.x + threadIdx.x;
    if (g < 4) { int2 p; p.x = 0; p.y = 0; edat[NE + g] = p; }
    int stride = gridDim.x * blockDim.x;
    for (int e = g; e < NE; e += stride) {
        int d = dst[e], r = rel[e];
        int pos = atomicAdd(&cursor[d * 4 + r], 1);
        int lb = (d & 15) * 4 + r;
        int2 v; v.x = src[e] | (lb << 20); v.y = __float_as_int(ew[e]);
        edat[pos] = v;
    }
}

// ---------------------------------------------------------------------------
// Conversions
// ---------------------------------------------------------------------------
__global__ __launch_bounds__(256) void k_cvt_x(
    const float* __restrict__ xf, unsigned short* __restrict__ xb)
{
    int i = blockIdx.x * 256 + threadIdx.x;
    if (i < NN * 64) xb[i] = f2bf(xf[i]);
}

__global__ __launch_bounds__(256) void k_cvt_w(
    const float* __restrict__ lin_w, const float* __restrict__ self_w,
    const float* __restrict__ pw, const float* __restrict__ tw,
    unsigned short* __restrict__ WL, unsigned short* __restrict__ WP,
    unsigned short* __restrict__ WT2)
{
    int id = blockIdx.x * 256 + threadIdx.x;   // 3*64*576
    if (id >= 3 * 64 * 576) return;
    int i = id / (64 * 576);
    int r = id % (64 * 576);
    int j = r / 576;
    int k = r % 576;
    if (k < 320) {
        float v = (k < 256) ? lin_w[((size_t)i * 256 + k) * 64 + j]
                            : self_w[((size_t)i * 64 + (k - 256)) * 64 + j];
        WL[((size_t)i * 64 + j) * 320 + k] = f2bf(v);
    } else if (k < 448) {
        int kk = k - 320;
        WP[((size_t)i * 64 + j) * 128 + kk] = f2bf(pw[((size_t)i * 128 + kk) * 64 + j]);
    } else {
        int kk = k - 448;
        WT2[((size_t)i * 64 + j) * 128 + kk] = f2bf(tw[((size_t)i * 128 + kk) * 64 + j]);
    }
}

// ---------------------------------------------------------------------------
// Fused layer with LDS-atomic aggregation (independent edge iterations).
// block = 256 threads = 4 waves = 16 nodes (64 (node,rel) buckets).
// sAf: f32 [16 rows][256 cols], XOR-swizzled (bit4) to keep ds_add (2-way)
// and ds_read_b128 fragment reads (2-way) conflict-free.
// ---------------------------------------------------------------------------
__global__ __launch_bounds__(256) void k_layer(
    const unsigned short* __restrict__ xb,
    const unsigned short* __restrict__ prevb,
    const int* __restrict__ row_ptr,
    const int2* __restrict__ edat,
    const unsigned short* __restrict__ WL,     // [64][320]
    const unsigned short* __restrict__ WP,     // [64][128]
    const unsigned short* __restrict__ WT2,    // [64][128]
    const float* __restrict__ lin_b, const float* __restrict__ self_b,
    const float* __restrict__ pb, const float* __restrict__ tb,
    unsigned short* __restrict__ hidb,
    unsigned short* __restrict__ gatedb,
    float* __restrict__ outf,
    int last)
{
    __shared__ __align__(16) float sAf[16 * 256];          // 16 KB
    __shared__ __align__(16) float sDeg[64];               // 256 B
    __shared__ __align__(16) unsigned short sX[16 * 64];   // 2 KB
    __shared__ __align__(16) unsigned short sH[16 * 128];  // 4 KB

    const int tid  = threadIdx.x;
    const int lane = tid & 63;
    const int wid  = tid >> 6;
    const int n0   = blockIdx.x * 16;
    const int hi   = lane >> 4;
    const int arow = lane & 15;
    const int bcol = wid * 16 + arow;

    // zero agg + deg
    #pragma unroll
    for (int i = 0; i < 16; ++i) sAf[tid + 256 * i] = 0.f;
    if (tid < 64) sDeg[tid] = 0.f;

    // stage prev into sH cols 64..127 (swizzled)
    #pragma unroll
    for (int j = 0; j < 4; ++j) {
        int idx = tid + 256 * j;
        int row = idx >> 6, col = idx & 63;
        int cb = (64 + col) * 2;
        *(unsigned short*)((char*)sH + row * 256 + (cb ^ ((row & 7) << 4))) =
            prevb[(size_t)(n0 + row) * 64 + col];
    }
    // stage x tile into sX (4 cols / thread, 8B swizzle-safe)
    {
        int row = tid >> 4;
        int c0  = (tid & 15) * 4;
        uint2 v = *(const uint2*)&xb[(size_t)(n0 + row) * 64 + c0];
        *(uint2*)((char*)sX + row * 128 + ((c0 * 2) ^ ((row & 7) << 4))) = v;
    }

    __syncthreads();

    // ---- edge loop: block's whole range split evenly across 4 waves ----
    int Eb0 = row_ptr[n0 * 4];
    int Eb1 = row_ptr[n0 * 4 + 64];
    int len = Eb1 - Eb0;
    int ebeg = Eb0 + ((len * wid) >> 2);
    int eend = Eb0 + ((len * (wid + 1)) >> 2);

    for (int e = ebeg; e < eend; e += 4) {
        int2 m0 = edat[e + 0];
        int2 m1 = edat[e + 1];
        int2 m2 = edat[e + 2];
        int2 m3 = edat[e + 3];
        #pragma unroll
        for (int j = 0; j < 4; ++j) {
            int2 m = (j == 0) ? m0 : (j == 1) ? m1 : (j == 2) ? m2 : m3;
            float w = (e + j < eend) ? __int_as_float(m.y) : 0.f;
            unsigned u = (unsigned)m.x;
            int srcn = (int)(u & 0xFFFFFu);
            int lb   = (int)(u >> 20);
            float xv = bf2f(xb[((size_t)srcn << 6) + lane]);
            float mv = xv * w;
            int r = lb >> 2;
            int byteoff = r * 1024 +
                (((((lb & 3) << 6) | lane) << 2) ^ ((r & 7) << 4));
            atomicAdd((float*)((char*)sAf + byteoff), mv);
            if (lane == 0) atomicAdd(&sDeg[lb], w);
        }
    }

    __syncthreads();

    // ---- per-lane reciprocal degrees (row = arow, rel 0..3) ----
    float4 dv = *(const float4*)((const char*)sDeg + arow * 16);
    float rd[4] = { 1.f / (dv.x + EPS), 1.f / (dv.y + EPS),
                    1.f / (dv.z + EPS), 1.f / (dv.w + EPS) };

    // conv B-fragments + biases
    bfrag8 bwL[10];
    #pragma unroll
    for (int ks = 0; ks < 10; ++ks)
        bwL[ks] = *(const bfrag8*)((const char*)WL + bcol * 640 + ks * 64 + hi * 16);
    float biasC = lin_b[bcol] + self_b[bcol];
    float pbv = pb[bcol], tbv = tb[bcol];

    // ---- conv MFMA: agg part (K=256) from sAf with fused normalize+cvt ----
    f4acc accC = {0.f, 0.f, 0.f, 0.f};
    const int swz = (arow & 7) << 4;
    const char* prow = (const char*)sAf + arow * 1024;
    #pragma unroll
    for (int ks = 0; ks < 8; ++ks) {
        int cb = (ks * 128 + hi * 32) ^ swz;
        float4 v0 = *(const float4*)(prow + cb);
        float4 v1 = *(const float4*)(prow + (cb ^ 16));
        float rdv = rd[ks >> 1];
        union { unsigned u[4]; bfrag8 f; } fa;
        asm("v_cvt_pk_bf16_f32 %0, %1, %2" : "=v"(fa.u[0]) : "v"(v0.x * rdv), "v"(v0.y * rdv));
        asm("v_cvt_pk_bf16_f32 %0, %1, %2" : "=v"(fa.u[1]) : "v"(v0.z * rdv), "v"(v0.w * rdv));
        asm("v_cvt_pk_bf16_f32 %0, %1, %2" : "=v"(fa.u[2]) : "v"(v1.x * rdv), "v"(v1.y * rdv));
        asm("v_cvt_pk_bf16_f32 %0, %1, %2" : "=v"(fa.u[3]) : "v"(v1.z * rdv), "v"(v1.w * rdv));
        accC = __builtin_amdgcn_mfma_f32_16x16x32_bf16(fa.f, bwL[ks], accC, 0, 0, 0);
    }
    // x part (K=64) from sX
    #pragma unroll
    for (int ks2 = 0; ks2 < 2; ++ks2) {
        bfrag8 a = *(const bfrag8*)((const char*)sX + arow * 128 +
                                    ((ks2 * 64 + hi * 16) ^ swz));
        accC = __builtin_amdgcn_mfma_f32_16x16x32_bf16(a, bwL[8 + ks2], accC, 0, 0, 0);
    }

    // highway B-fragments
    bfrag8 bwP[4], bwT[4];
    #pragma unroll
    for (int ks = 0; ks < 4; ++ks) {
        bwP[ks] = *(const bfrag8*)((const char*)WP  + bcol * 256 + ks * 64 + hi * 16);
        bwT[ks] = *(const bfrag8*)((const char*)WT2 + bcol * 256 + ks * 64 + hi * 16);
    }

    // sigmoid; stage hid into sH cols 0..63; store hidden bf16
    float hid[4];
    #pragma unroll
    for (int q = 0; q < 4; ++q) {
        float o = accC[q] + biasC;
        hid[q] = 1.f / (1.f + __expf(-o));
        int row = hi * 4 + q;
        unsigned short hb = f2bf(hid[q]);
        *(unsigned short*)((char*)sH + row * 256 + ((bcol * 2) ^ ((row & 7) << 4))) = hb;
        hidb[(size_t)(n0 + row) * 64 + bcol] = hb;
    }

    __syncthreads();

    // ---- highway MFMA: cat=[hid, prev], K = 128 ----
    f4acc accP = {0.f, 0.f, 0.f, 0.f};
    f4acc accT = {0.f, 0.f, 0.f, 0.f};
    #pragma unroll
    for (int ks = 0; ks < 4; ++ks) {
        bfrag8 a = *(const bfrag8*)((const char*)sH + arow * 256 +
                                    ((ks * 64 + hi * 16) ^ swz));
        accP = __builtin_amdgcn_mfma_f32_16x16x32_bf16(a, bwP[ks], accP, 0, 0, 0);
        accT = __builtin_amdgcn_mfma_f32_16x16x32_bf16(a, bwT[ks], accT, 0, 0, 0);
    }

    #pragma unroll
    for (int q = 0; q < 4; ++q) {
        float proj = fmaxf(accP[q] + pbv, 0.f);
        float gate = 1.f / (1.f + __expf(-(accT[q] + tbv)));
        float o = gate * proj + (1.f - gate) * hid[q];
        int row = hi * 4 + q;
        if (last) outf[(size_t)(n0 + row) * 64 + bcol] = o;
        else      gatedb[(size_t)(n0 + row) * 64 + bcol] = f2bf(o);
    }
}

// ---------------------------------------------------------------------------
extern "C" void kernel_launch(void* const* d_in, const int* in_sizes, int n_in,
                              void* d_out, int out_size, void* d_ws, size_t ws_size,
                              hipStream_t stream)
{
    const float* node_feat = (const float*)d_in[0];
    const float* ew        = (const float*)d_in[1];
    const float* lin_w     = (const float*)d_in[2];
    const float* lin_b     = (const float*)d_in[3];
    const float* self_w    = (const float*)d_in[4];
    const float* self_b    = (const float*)d_in[5];
    const float* pw        = (const float*)d_in[6];
    const float* pb        = (const float*)d_in[7];
    const float* tw        = (const float*)d_in[8];
    const float* tb        = (const float*)d_in[9];
    const int*   src       = (const int*)d_in[10];
    const int*   dst       = (const int*)d_in[11];
    const int*   rel       = (const int*)d_in[12];
    float* outf = (float*)d_out;

    char* ws = (char*)d_ws;
    int*            row_ptr = (int*)(ws + 0);
    int*            cnt     = (int*)(ws + 1600256);
    int*            cursor  = (int*)(ws + 3200256);
    int2*           edat    = (int2*)(ws + 4800256);            // (NE+4)*8
    unsigned short* nfb     = (unsigned short*)(ws + 17600512);
    unsigned short* hbfA    = (unsigned short*)(ws + 30400512);
    unsigned short* hbfB    = (unsigned short*)(ws + 43200512);
    unsigned short* gbfA    = (unsigned short*)(ws + 56000512);
    unsigned short* gbfB    = (unsigned short*)(ws + 68800512);
    unsigned short* WL      = (unsigned short*)(ws + 81600512);
    unsigned short* WP      = (unsigned short*)(ws + 81600512 + 122880);
    unsigned short* WT2     = (unsigned short*)(ws + 81600512 + 122880 + 49152);
    int*            blksum  = (int*)(ws + 81600512 + 122880 + 49152 + 49152);
    int*            blkoff  = blksum + 512;

    // CSR build (layer-invariant)
    hipMemsetAsync(cnt, 0, NB * sizeof(int), stream);
    k_hist<<<2048, 256, 0, stream>>>(dst, rel, cnt);
    k_scan_local<<<NBLK_SCAN, 1024, 0, stream>>>(cnt, row_ptr, blksum);
    k_scan_blk<<<1, 512, 0, stream>>>(blksum, blkoff, row_ptr);
    k_scan_add<<<NBLK_SCAN, 1024, 0, stream>>>(row_ptr, blkoff, cursor);
    k_reorder<<<2048, 256, 0, stream>>>(src, dst, rel, ew, cursor, edat);

    // bf16 conversions
    k_cvt_x<<<25000, 256, 0, stream>>>(node_feat, nfb);
    k_cvt_w<<<432, 256, 0, stream>>>(lin_w, self_w, pw, tw, WL, WP, WT2);

    const unsigned short* cur  = nfb;
    const unsigned short* prev = nfb;
    unsigned short* hbuf[3] = { hbfA, hbfB, hbfA };
    unsigned short* gbuf[3] = { gbfA, gbfB, gbfA };

    for (int i = 0; i < 3; ++i) {
        int lastL = (i == 2);
        k_layer<<<NN / 16, 256, 0, stream>>>(
            cur, prev, row_ptr, edat,
            WL  + (size_t)i * 64 * 320,
            WP  + (size_t)i * 64 * 128,
            WT2 + (size_t)i * 64 * 128,
            lin_b + (size_t)i * 64, self_b + (size_t)i * 64,
            pb + (size_t)i * 64, tb + (size_t)i * 64,
            hbuf[i], gbuf[i], outf, lastL);
        cur  = gbuf[i];
        prev = hbuf[i];
    }
}

// Round 6
// 509.246 us; speedup vs baseline: 3.7328x; 3.7328x over previous
//
#include <hip/hip_runtime.h>

#define NN   100000
#define NE   1600000
#define NB   400000     // NN*4 (dst,rel) segments
#define EPS  1e-10f

#define NBLK_SCAN 391   // ceil(NB/1024)

typedef __attribute__((ext_vector_type(8))) short bfrag8;
typedef __attribute__((ext_vector_type(4))) float f4acc;

__device__ __forceinline__ unsigned short f2bf(float f) {
    union { float f; unsigned u; } v; v.f = f;
    unsigned r = v.u + 0x7FFF + ((v.u >> 16) & 1);
    return (unsigned short)(r >> 16);
}
__device__ __forceinline__ float bf2f(unsigned short b) {
    union { unsigned u; float f; } v; v.u = ((unsigned)b) << 16;
    return v.f;
}

// ---------------------------------------------------------------------------
// CSR build: key = dst*4 + rel  (400K segments)
// ---------------------------------------------------------------------------
__global__ __launch_bounds__(256) void k_hist(
    const int* __restrict__ dst, const int* __restrict__ rel,
    int* __restrict__ cnt)
{
    int stride = gridDim.x * blockDim.x;
    for (int e = blockIdx.x * blockDim.x + threadIdx.x; e < NE; e += stride)
        atomicAdd(&cnt[dst[e] * 4 + rel[e]], 1);
}

__global__ __launch_bounds__(1024) void k_scan_local(
    const int* __restrict__ cnt, int* __restrict__ row_ptr,
    int* __restrict__ blksum)
{
    __shared__ int s[1024];
    int t = threadIdx.x;
    int i = blockIdx.x * 1024 + t;
    int v = (i < NB) ? cnt[i] : 0;
    s[t] = v;
    __syncthreads();
    #pragma unroll
    for (int off = 1; off < 1024; off <<= 1) {
        int u = (t >= off) ? s[t - off] : 0;
        __syncthreads();
        s[t] += u;
        __syncthreads();
    }
    if (i < NB) row_ptr[i] = s[t] - v;
    if (t == 1023) blksum[blockIdx.x] = s[t];
}

__global__ __launch_bounds__(512) void k_scan_blk(
    int* __restrict__ blksum, int* __restrict__ blkoff, int* __restrict__ row_ptr)
{
    __shared__ int s[512];
    int t = threadIdx.x;
    int v = (t < NBLK_SCAN) ? blksum[t] : 0;
    s[t] = v;
    __syncthreads();
    #pragma unroll
    for (int off = 1; off < 512; off <<= 1) {
        int u = (t >= off) ? s[t - off] : 0;
        __syncthreads();
        s[t] += u;
        __syncthreads();
    }
    if (t < NBLK_SCAN) blkoff[t] = s[t] - v;
    if (t == NBLK_SCAN - 1) row_ptr[NB] = s[t];
}

__global__ __launch_bounds__(1024) void k_scan_add(
    int* __restrict__ row_ptr, const int* __restrict__ blkoff,
    int* __restrict__ cursor)
{
    int i = blockIdx.x * 1024 + threadIdx.x;
    if (i < NB) {
        int v = row_ptr[i] + blkoff[blockIdx.x];
        row_ptr[i] = v;
        cursor[i] = v;
    }
}

// reorder into (dst,rel)-sorted order; 32 zero pad entries past NE so the
// layer kernel's software pipeline can safely over-read.
__global__ __launch_bounds__(256) void k_reorder(
    const int* __restrict__ src, const int* __restrict__ dst,
    const int* __restrict__ rel, const float* __restrict__ ew,
    int* __restrict__ cursor, int2* __restrict__ edat)
{
    int g = blockIdx.x * blockDim.x + threadIdx.x;
    if (g < 32) { int2 p; p.x = 0; p.y = 0; edat[NE + g] = p; }
    int stride = gridDim.x * blockDim.x;
    for (int e = g; e < NE; e += stride) {
        int pos = atomicAdd(&cursor[dst[e] * 4 + rel[e]], 1);
        int2 v; v.x = src[e]; v.y = __float_as_int(ew[e]);
        edat[pos] = v;
    }
}

// ---------------------------------------------------------------------------
// Conversions
// ---------------------------------------------------------------------------
__global__ __launch_bounds__(256) void k_cvt_x(
    const float* __restrict__ xf, unsigned short* __restrict__ xb)
{
    int i = blockIdx.x * 256 + threadIdx.x;
    if (i < NN * 64) xb[i] = f2bf(xf[i]);
}

__global__ __launch_bounds__(256) void k_cvt_w(
    const float* __restrict__ lin_w, const float* __restrict__ self_w,
    const float* __restrict__ pw, const float* __restrict__ tw,
    unsigned short* __restrict__ WL, unsigned short* __restrict__ WP,
    unsigned short* __restrict__ WT2)
{
    int id = blockIdx.x * 256 + threadIdx.x;   // 3*64*576
    if (id >= 3 * 64 * 576) return;
    int i = id / (64 * 576);
    int r = id % (64 * 576);
    int j = r / 576;
    int k = r % 576;
    if (k < 320) {
        float v = (k < 256) ? lin_w[((size_t)i * 256 + k) * 64 + j]
                            : self_w[((size_t)i * 64 + (k - 256)) * 64 + j];
        WL[((size_t)i * 64 + j) * 320 + k] = f2bf(v);
    } else if (k < 448) {
        int kk = k - 320;
        WP[((size_t)i * 64 + j) * 128 + kk] = f2bf(pw[((size_t)i * 128 + kk) * 64 + j]);
    } else {
        int kk = k - 448;
        WT2[((size_t)i * 64 + j) * 128 + kk] = f2bf(tw[((size_t)i * 128 + kk) * 64 + j]);
    }
}

// ---------------------------------------------------------------------------
// Fused layer: depth-8 pipelined edge-aggregate -> conv MFMA -> sigmoid
// -> highway MFMA -> gated.  block = 256 threads = 4 waves, 16 nodes.
// ---------------------------------------------------------------------------
__global__ __launch_bounds__(256, 4) void k_layer(
    const unsigned short* __restrict__ xb,     // layer input bf16 [NN][64]
    const unsigned short* __restrict__ prevb,  // prev hidden bf16 [NN][64]
    const int* __restrict__ row_ptr,
    const int2* __restrict__ edat,
    const unsigned short* __restrict__ WL,     // [64][320]
    const unsigned short* __restrict__ WP,     // [64][128]
    const unsigned short* __restrict__ WT2,    // [64][128]
    const float* __restrict__ lin_b, const float* __restrict__ self_b,
    const float* __restrict__ pb, const float* __restrict__ tb,
    unsigned short* __restrict__ hidb,
    unsigned short* __restrict__ gatedb,
    float* __restrict__ outf,
    int last)
{
    __shared__ __align__(16) unsigned short sA[16 * 320];  // 10240 B
    __shared__ __align__(16) unsigned short sH[16 * 128];  //  4096 B
    __shared__ int sRP[65];

    const int tid  = threadIdx.x;
    const int lane = tid & 63;
    const int wid  = tid >> 6;
    const int n0   = blockIdx.x * 16;
    const int bcol = wid * 16 + (lane & 15);        // output column
    const int koff2 = (lane >> 4) * 16;             // byte offset of 8-elem k group
    const int arow = lane & 15;

    // ---- row_ptr window for this block's 64 segments ----
    if (tid < 65) sRP[tid] = row_ptr[n0 * 4 + tid];

    // ---- prev staging into sH cols 64..127 (block-wide) ----
    #pragma unroll
    for (int j = 0; j < 4; ++j) {
        int idx = tid + 256 * j;                    // 0..1023
        int row = idx >> 6, col = idx & 63;
        int cb = (64 + col) * 2;
        *(unsigned short*)((char*)sH + row * 256 + (cb ^ ((row & 7) << 4))) =
            prevb[(size_t)(n0 + row) * 64 + col];
    }
    // ---- x rows into sA cols 256..319 (wave's 4 nodes) ----
    #pragma unroll
    for (int j = 0; j < 4; ++j) {
        int ln = wid * 4 + j;
        int cb = (256 + lane) * 2;
        *(unsigned short*)((char*)sA + ln * 640 + (cb ^ ((ln & 7) << 4))) =
            xb[(size_t)(n0 + ln) * 64 + lane];
    }

    __syncthreads();

    // ---- edge aggregation over the wave's 16 contiguous segments,
    //      software-pipelined: 8 outstanding gathers + meta 2 groups ahead ----
    const int sbase = wid * 16;
    int E0 = sRP[sbase];
    int E1 = sRP[sbase + 16];
    int seg = 0;
    int segEnd = sRP[sbase + 1];
    float acc = 0.f, dsum = 0.f;

    int2 cm[8], nm[8];
    unsigned short cx[8], nx[8];

    #pragma unroll
    for (int j = 0; j < 8; ++j) cm[j] = edat[E0 + j];
    #pragma unroll
    for (int j = 0; j < 8; ++j)
        cx[j] = xb[((size_t)(unsigned)cm[j].x << 6) + lane];
    #pragma unroll
    for (int j = 0; j < 8; ++j) nm[j] = edat[E0 + 8 + j];

    for (int e = E0; e < E1; e += 8) {
        // gathers for group i+1 (meta already resident)
        #pragma unroll
        for (int j = 0; j < 8; ++j)
            nx[j] = xb[((size_t)(unsigned)nm[j].x << 6) + lane];
        // meta for group i+2
        int2 nnm[8];
        #pragma unroll
        for (int j = 0; j < 8; ++j) nnm[j] = edat[e + 16 + j];
        // accumulate group i
        #pragma unroll
        for (int j = 0; j < 8; ++j) {
            int idx = e + j;
            if (idx < E1) {                           // wave-uniform branch
                while (idx >= segEnd) {               // flush finished segments
                    float u = acc / (dsum + EPS);
                    int ln = wid * 4 + (seg >> 2);
                    int cb = ((seg & 3) * 64 + lane) * 2;
                    *(unsigned short*)((char*)sA + ln * 640 +
                                       (cb ^ ((ln & 7) << 4))) = f2bf(u);
                    acc = 0.f; dsum = 0.f;
                    ++seg; segEnd = sRP[sbase + seg + 1];
                }
                float w = __int_as_float(cm[j].y);
                acc = fmaf(bf2f(cx[j]), w, acc);
                dsum += w;
            }
        }
        #pragma unroll
        for (int j = 0; j < 8; ++j) { cm[j] = nm[j]; cx[j] = nx[j]; nm[j] = nnm[j]; }
    }
    while (seg < 16) {                                 // trailing flush
        float u = acc / (dsum + EPS);
        int ln = wid * 4 + (seg >> 2);
        int cb = ((seg & 3) * 64 + lane) * 2;
        *(unsigned short*)((char*)sA + ln * 640 + (cb ^ ((ln & 7) << 4))) = f2bf(u);
        acc = 0.f; dsum = 0.f;
        ++seg;
    }

    // ---- conv B-fragments (issued before barrier) ----
    bfrag8 bwL[10];
    #pragma unroll
    for (int ks = 0; ks < 10; ++ks)
        bwL[ks] = *(const bfrag8*)((const char*)WL + bcol * 640 + ks * 64 + koff2);
    float biasC = lin_b[bcol] + self_b[bcol];
    float pbv = pb[bcol], tbv = tb[bcol];

    __syncthreads();

    // ---- conv MFMA: wave computes cols [wid*16, wid*16+16), K = 320 ----
    f4acc accC = {0.f, 0.f, 0.f, 0.f};
    #pragma unroll
    for (int ks = 0; ks < 10; ++ks) {
        bfrag8 a = *(const bfrag8*)((const char*)sA + arow * 640 +
                                    ((ks * 64 + koff2) ^ ((arow & 7) << 4)));
        accC = __builtin_amdgcn_mfma_f32_16x16x32_bf16(a, bwL[ks], accC, 0, 0, 0);
    }

    // highway B-fragments
    bfrag8 bwP[4], bwT[4];
    #pragma unroll
    for (int ks = 0; ks < 4; ++ks) {
        bwP[ks] = *(const bfrag8*)((const char*)WP  + bcol * 256 + ks * 64 + koff2);
        bwT[ks] = *(const bfrag8*)((const char*)WT2 + bcol * 256 + ks * 64 + koff2);
    }

    // sigmoid epilogue; stage hid into sH cols 0..63; store hidden bf16
    float hid[4];
    #pragma unroll
    for (int q = 0; q < 4; ++q) {
        float o = accC[q] + biasC;
        hid[q] = 1.f / (1.f + __expf(-o));
        int row = (lane >> 4) * 4 + q;
        unsigned short hb = f2bf(hid[q]);
        *(unsigned short*)((char*)sH + row * 256 + ((bcol * 2) ^ ((row & 7) << 4))) = hb;
        hidb[(size_t)(n0 + row) * 64 + bcol] = hb;
    }

    __syncthreads();

    // ---- highway MFMA: cat=[hid, prev], K = 128 ----
    f4acc accP = {0.f, 0.f, 0.f, 0.f};
    f4acc accT = {0.f, 0.f, 0.f, 0.f};
    #pragma unroll
    for (int ks = 0; ks < 4; ++ks) {
        bfrag8 a = *(const bfrag8*)((const char*)sH + arow * 256 +
                                    ((ks * 64 + koff2) ^ ((arow & 7) << 4)));
        accP = __builtin_amdgcn_mfma_f32_16x16x32_bf16(a, bwP[ks], accP, 0, 0, 0);
        accT = __builtin_amdgcn_mfma_f32_16x16x32_bf16(a, bwT[ks], accT, 0, 0, 0);
    }

    #pragma unroll
    for (int q = 0; q < 4; ++q) {
        float proj = fmaxf(accP[q] + pbv, 0.f);
        float gate = 1.f / (1.f + __expf(-(accT[q] + tbv)));
        float o = gate * proj + (1.f - gate) * hid[q];
        int row = (lane >> 4) * 4 + q;
        if (last) outf[(size_t)(n0 + row) * 64 + bcol] = o;
        else      gatedb[(size_t)(n0 + row) * 64 + bcol] = f2bf(o);
    }
}

// ---------------------------------------------------------------------------
extern "C" void kernel_launch(void* const* d_in, const int* in_sizes, int n_in,
                              void* d_out, int out_size, void* d_ws, size_t ws_size,
                              hipStream_t stream)
{
    const float* node_feat = (const float*)d_in[0];
    const float* ew        = (const float*)d_in[1];
    const float* lin_w     = (const float*)d_in[2];
    const float* lin_b     = (const float*)d_in[3];
    const float* self_w    = (const float*)d_in[4];
    const float* self_b    = (const float*)d_in[5];
    const float* pw        = (const float*)d_in[6];
    const float* pb        = (const float*)d_in[7];
    const float* tw        = (const float*)d_in[8];
    const float* tb        = (const float*)d_in[9];
    const int*   src       = (const int*)d_in[10];
    const int*   dst       = (const int*)d_in[11];
    const int*   rel       = (const int*)d_in[12];
    float* outf = (float*)d_out;

    char* ws = (char*)d_ws;
    int*            row_ptr = (int*)(ws + 0);
    int*            cnt     = (int*)(ws + 1600256);
    int*            cursor  = (int*)(ws + 3200256);
    int2*           edat    = (int2*)(ws + 4800256);            // (NE+32)*8
    unsigned short* nfb     = (unsigned short*)(ws + 17600512);
    unsigned short* hbfA    = (unsigned short*)(ws + 30400512);
    unsigned short* hbfB    = (unsigned short*)(ws + 43200512);
    unsigned short* gbfA    = (unsigned short*)(ws + 56000512);
    unsigned short* gbfB    = (unsigned short*)(ws + 68800512);
    unsigned short* WL      = (unsigned short*)(ws + 81600512);
    unsigned short* WP      = (unsigned short*)(ws + 81600512 + 122880);
    unsigned short* WT2     = (unsigned short*)(ws + 81600512 + 122880 + 49152);
    int*            blksum  = (int*)(ws + 81600512 + 122880 + 49152 + 49152);
    int*            blkoff  = blksum + 512;

    // CSR build (layer-invariant)
    hipMemsetAsync(cnt, 0, NB * sizeof(int), stream);
    k_hist<<<2048, 256, 0, stream>>>(dst, rel, cnt);
    k_scan_local<<<NBLK_SCAN, 1024, 0, stream>>>(cnt, row_ptr, blksum);
    k_scan_blk<<<1, 512, 0, stream>>>(blksum, blkoff, row_ptr);
    k_scan_add<<<NBLK_SCAN, 1024, 0, stream>>>(row_ptr, blkoff, cursor);
    k_reorder<<<2048, 256, 0, stream>>>(src, dst, rel, ew, cursor, edat);

    // bf16 conversions
    k_cvt_x<<<25000, 256, 0, stream>>>(node_feat, nfb);
    k_cvt_w<<<432, 256, 0, stream>>>(lin_w, self_w, pw, tw, WL, WP, WT2);

    const unsigned short* cur  = nfb;
    const unsigned short* prev = nfb;
    unsigned short* hbuf[3] = { hbfA, hbfB, hbfA };
    unsigned short* gbuf[3] = { gbfA, gbfB, gbfA };

    for (int i = 0; i < 3; ++i) {
        int lastL = (i == 2);
        k_layer<<<NN / 16, 256, 0, stream>>>(
            cur, prev, row_ptr, edat,
            WL  + (size_t)i * 64 * 320,
            WP  + (size_t)i * 64 * 128,
            WT2 + (size_t)i * 64 * 128,
            lin_b + (size_t)i * 64, self_b + (size_t)i * 64,
            pb + (size_t)i * 64, tb + (size_t)i * 64,
            hbuf[i], gbuf[i], outf, lastL);
        cur  = gbuf[i];
        prev = hbuf[i];
    }
}

// Round 7
// 443.390 us; speedup vs baseline: 4.2872x; 1.1485x over previous
//
#include <hip/hip_runtime.h>

#define NN   100000
#define NE   1600000
#define NB   400000     // NN*4 (dst,rel) segments
#define EPS  1e-10f

#define NCHK  256       // edge chunks (phase A blocks)
#define EPC   6250      // NE / NCHK
#define NBUCK 391       // coarse buckets: dst>>8  (ceil(100000/256))
#define NHBC  (NBUCK * NCHK)   // 100096

typedef __attribute__((ext_vector_type(8))) short bfrag8;
typedef __attribute__((ext_vector_type(4))) float f4acc;

__device__ __forceinline__ unsigned short f2bf(float f) {
    union { float f; unsigned u; } v; v.f = f;
    unsigned r = v.u + 0x7FFF + ((v.u >> 16) & 1);
    return (unsigned short)(r >> 16);
}
__device__ __forceinline__ float bf2f(unsigned short b) {
    union { unsigned u; float f; } v; v.u = ((unsigned)b) << 16;
    return v.f;
}

// ---------------------------------------------------------------------------
// Phase A1: per-(bucket,chunk) histogram in LDS  +  400K segment histogram
// ---------------------------------------------------------------------------
__global__ __launch_bounds__(256) void kA1(
    const int* __restrict__ dst, const int* __restrict__ rel,
    int* __restrict__ cnt_seg, int* __restrict__ histBC)
{
    __shared__ int s_h[NBUCK];
    for (int i = threadIdx.x; i < NBUCK; i += 256) s_h[i] = 0;
    __syncthreads();
    int e0 = blockIdx.x * EPC;
    for (int e = e0 + threadIdx.x; e < e0 + EPC; e += 256) {
        int d = dst[e];
        atomicAdd(&s_h[d >> 8], 1);
        atomicAdd(&cnt_seg[d * 4 + rel[e]], 1);
    }
    __syncthreads();
    for (int i = threadIdx.x; i < NBUCK; i += 256)
        histBC[i * NCHK + blockIdx.x] = s_h[i];   // bucket-major
}

// --- generic coalesced 3-phase scan ----------------------------------------
__global__ __launch_bounds__(1024) void k_scan_local_g(
    const int* __restrict__ in, int* __restrict__ out,
    int* __restrict__ blksum, int n)
{
    __shared__ int s[1024];
    int t = threadIdx.x;
    int i = blockIdx.x * 1024 + t;
    int v = (i < n) ? in[i] : 0;
    s[t] = v;
    __syncthreads();
    #pragma unroll
    for (int off = 1; off < 1024; off <<= 1) {
        int u = (t >= off) ? s[t - off] : 0;
        __syncthreads();
        s[t] += u;
        __syncthreads();
    }
    if (i < n) out[i] = s[t] - v;
    if (t == 1023) blksum[blockIdx.x] = s[t];
}

__global__ __launch_bounds__(512) void k_scan_blk_g(
    int* __restrict__ blksum, int* __restrict__ blkoff,
    int nblk, int* __restrict__ total_dst)
{
    __shared__ int s[512];
    int t = threadIdx.x;
    int v = (t < nblk) ? blksum[t] : 0;
    s[t] = v;
    __syncthreads();
    #pragma unroll
    for (int off = 1; off < 512; off <<= 1) {
        int u = (t >= off) ? s[t - off] : 0;
        __syncthreads();
        s[t] += u;
        __syncthreads();
    }
    if (t < nblk) blkoff[t] = s[t] - v;
    if (total_dst && t == nblk - 1) *total_dst = s[t];
}

__global__ __launch_bounds__(1024) void k_scan_add_g(
    int* __restrict__ out, const int* __restrict__ blkoff, int n)
{
    int i = blockIdx.x * 1024 + threadIdx.x;
    if (i < n) out[i] += blkoff[blockIdx.x];
}

// ---------------------------------------------------------------------------
// Phase A3: partition edges into coarse buckets (line-dense writes).
// record: .x = src | seg_local<<20   (seg_local = (dst&255)*4+rel, 10 bits)
// ---------------------------------------------------------------------------
__global__ __launch_bounds__(256) void kA3(
    const int* __restrict__ src, const int* __restrict__ dst,
    const int* __restrict__ rel, const float* __restrict__ ew,
    const int* __restrict__ chunkOff, int2* __restrict__ pA)
{
    __shared__ int s_c[NBUCK];
    for (int i = threadIdx.x; i < NBUCK; i += 256)
        s_c[i] = chunkOff[i * NCHK + blockIdx.x];
    __syncthreads();
    int e0 = blockIdx.x * EPC;
    for (int e = e0 + threadIdx.x; e < e0 + EPC; e += 256) {
        int d = dst[e], r = rel[e];
        int pos = atomicAdd(&s_c[d >> 8], 1);
        int2 v;
        v.x = src[e] | (((d & 255) * 4 + r) << 20);
        v.y = __float_as_int(ew[e]);
        pA[pos] = v;
    }
}

// ---------------------------------------------------------------------------
// Phase B: one block per bucket; in-bucket counting sort by seg_local.
// Reads coalesced; writes confined to the bucket's ~32 KB L2-hot region.
// ---------------------------------------------------------------------------
__global__ __launch_bounds__(256) void kB(
    const int* __restrict__ row_ptr, const int2* __restrict__ pA,
    int2* __restrict__ edat)
{
    __shared__ int s_c[1024];
    __shared__ int s_p[256];
    const int b    = blockIdx.x;
    const int t    = threadIdx.x;
    const int seg0 = b * 1024;
    const int segN = min(1024, NB - seg0);
    const int pbeg = row_ptr[seg0];
    const int pend = row_ptr[seg0 + segN];

    for (int i = t; i < 1024; i += 256) s_c[i] = 0;
    __syncthreads();
    for (int p = pbeg + t; p < pend; p += 256)
        atomicAdd(&s_c[((unsigned)pA[p].x) >> 20], 1);
    __syncthreads();

    // exclusive scan of s_c[1024] with 256 threads
    int c0 = s_c[t * 4], c1 = s_c[t * 4 + 1], c2 = s_c[t * 4 + 2], c3 = s_c[t * 4 + 3];
    int tsum = c0 + c1 + c2 + c3;
    s_p[t] = tsum;
    __syncthreads();
    #pragma unroll
    for (int off = 1; off < 256; off <<= 1) {
        int u = (t >= off) ? s_p[t - off] : 0;
        __syncthreads();
        s_p[t] += u;
        __syncthreads();
    }
    int base = s_p[t] - tsum;
    s_c[t * 4]     = base;
    s_c[t * 4 + 1] = base + c0;
    s_c[t * 4 + 2] = base + c0 + c1;
    s_c[t * 4 + 3] = base + c0 + c1 + c2;
    __syncthreads();

    for (int p = pbeg + t; p < pend; p += 256) {
        int2 v = pA[p];
        int sl = ((unsigned)v.x) >> 20;
        int pos = atomicAdd(&s_c[sl], 1);
        int2 o; o.x = v.x & 0xFFFFF; o.y = v.y;
        edat[pbeg + pos] = o;
    }
    if (b == 0 && t < 32) { int2 z; z.x = 0; z.y = 0; edat[NE + t] = z; }
}

// ---------------------------------------------------------------------------
// Conversions
// ---------------------------------------------------------------------------
__global__ __launch_bounds__(256) void k_cvt_x(
    const float* __restrict__ xf, unsigned short* __restrict__ xb)
{
    int i = blockIdx.x * 256 + threadIdx.x;
    if (i < NN * 64) xb[i] = f2bf(xf[i]);
}

__global__ __launch_bounds__(256) void k_cvt_w(
    const float* __restrict__ lin_w, const float* __restrict__ self_w,
    const float* __restrict__ pw, const float* __restrict__ tw,
    unsigned short* __restrict__ WL, unsigned short* __restrict__ WP,
    unsigned short* __restrict__ WT2)
{
    int id = blockIdx.x * 256 + threadIdx.x;   // 3*64*576
    if (id >= 3 * 64 * 576) return;
    int i = id / (64 * 576);
    int r = id % (64 * 576);
    int j = r / 576;
    int k = r % 576;
    if (k < 320) {
        float v = (k < 256) ? lin_w[((size_t)i * 256 + k) * 64 + j]
                            : self_w[((size_t)i * 64 + (k - 256)) * 64 + j];
        WL[((size_t)i * 64 + j) * 320 + k] = f2bf(v);
    } else if (k < 448) {
        int kk = k - 320;
        WP[((size_t)i * 64 + j) * 128 + kk] = f2bf(pw[((size_t)i * 128 + kk) * 64 + j]);
    } else {
        int kk = k - 448;
        WT2[((size_t)i * 64 + j) * 128 + kk] = f2bf(tw[((size_t)i * 128 + kk) * 64 + j]);
    }
}

// ---------------------------------------------------------------------------
// Fused layer: depth-8 pipelined edge-aggregate -> conv MFMA -> sigmoid
// -> highway MFMA -> gated.  block = 256 threads = 4 waves, 16 nodes.
// ---------------------------------------------------------------------------
__global__ __launch_bounds__(256, 4) void k_layer(
    const unsigned short* __restrict__ xb,     // layer input bf16 [NN][64]
    const unsigned short* __restrict__ prevb,  // prev hidden bf16 [NN][64]
    const int* __restrict__ row_ptr,
    const int2* __restrict__ edat,
    const unsigned short* __restrict__ WL,     // [64][320]
    const unsigned short* __restrict__ WP,     // [64][128]
    const unsigned short* __restrict__ WT2,    // [64][128]
    const float* __restrict__ lin_b, const float* __restrict__ self_b,
    const float* __restrict__ pb, const float* __restrict__ tb,
    unsigned short* __restrict__ hidb,
    unsigned short* __restrict__ gatedb,
    float* __restrict__ outf,
    int last)
{
    __shared__ __align__(16) unsigned short sA[16 * 320];  // 10240 B
    __shared__ __align__(16) unsigned short sH[16 * 128];  //  4096 B
    __shared__ int sRP[65];

    const int tid  = threadIdx.x;
    const int lane = tid & 63;
    const int wid  = tid >> 6;
    const int n0   = blockIdx.x * 16;
    const int bcol = wid * 16 + (lane & 15);
    const int koff2 = (lane >> 4) * 16;
    const int arow = lane & 15;

    if (tid < 65) sRP[tid] = row_ptr[n0 * 4 + tid];

    #pragma unroll
    for (int j = 0; j < 4; ++j) {
        int idx = tid + 256 * j;
        int row = idx >> 6, col = idx & 63;
        int cb = (64 + col) * 2;
        *(unsigned short*)((char*)sH + row * 256 + (cb ^ ((row & 7) << 4))) =
            prevb[(size_t)(n0 + row) * 64 + col];
    }
    #pragma unroll
    for (int j = 0; j < 4; ++j) {
        int ln = wid * 4 + j;
        int cb = (256 + lane) * 2;
        *(unsigned short*)((char*)sA + ln * 640 + (cb ^ ((ln & 7) << 4))) =
            xb[(size_t)(n0 + ln) * 64 + lane];
    }

    __syncthreads();

    const int sbase = wid * 16;
    int E0 = sRP[sbase];
    int E1 = sRP[sbase + 16];
    int seg = 0;
    int segEnd = sRP[sbase + 1];
    float acc = 0.f, dsum = 0.f;

    int2 cm[8], nm[8];
    unsigned short cx[8], nx[8];

    #pragma unroll
    for (int j = 0; j < 8; ++j) cm[j] = edat[E0 + j];
    #pragma unroll
    for (int j = 0; j < 8; ++j)
        cx[j] = xb[((size_t)(unsigned)cm[j].x << 6) + lane];
    #pragma unroll
    for (int j = 0; j < 8; ++j) nm[j] = edat[E0 + 8 + j];

    for (int e = E0; e < E1; e += 8) {
        #pragma unroll
        for (int j = 0; j < 8; ++j)
            nx[j] = xb[((size_t)(unsigned)nm[j].x << 6) + lane];
        int2 nnm[8];
        #pragma unroll
        for (int j = 0; j < 8; ++j) nnm[j] = edat[e + 16 + j];
        #pragma unroll
        for (int j = 0; j < 8; ++j) {
            int idx = e + j;
            if (idx < E1) {
                while (idx >= segEnd) {
                    float u = acc / (dsum + EPS);
                    int ln = wid * 4 + (seg >> 2);
                    int cb = ((seg & 3) * 64 + lane) * 2;
                    *(unsigned short*)((char*)sA + ln * 640 +
                                       (cb ^ ((ln & 7) << 4))) = f2bf(u);
                    acc = 0.f; dsum = 0.f;
                    ++seg; segEnd = sRP[sbase + seg + 1];
                }
                float w = __int_as_float(cm[j].y);
                acc = fmaf(bf2f(cx[j]), w, acc);
                dsum += w;
            }
        }
        #pragma unroll
        for (int j = 0; j < 8; ++j) { cm[j] = nm[j]; cx[j] = nx[j]; nm[j] = nnm[j]; }
    }
    while (seg < 16) {
        float u = acc / (dsum + EPS);
        int ln = wid * 4 + (seg >> 2);
        int cb = ((seg & 3) * 64 + lane) * 2;
        *(unsigned short*)((char*)sA + ln * 640 + (cb ^ ((ln & 7) << 4))) = f2bf(u);
        acc = 0.f; dsum = 0.f;
        ++seg;
    }

    bfrag8 bwL[10];
    #pragma unroll
    for (int ks = 0; ks < 10; ++ks)
        bwL[ks] = *(const bfrag8*)((const char*)WL + bcol * 640 + ks * 64 + koff2);
    float biasC = lin_b[bcol] + self_b[bcol];
    float pbv = pb[bcol], tbv = tb[bcol];

    __syncthreads();

    f4acc accC = {0.f, 0.f, 0.f, 0.f};
    #pragma unroll
    for (int ks = 0; ks < 10; ++ks) {
        bfrag8 a = *(const bfrag8*)((const char*)sA + arow * 640 +
                                    ((ks * 64 + koff2) ^ ((arow & 7) << 4)));
        accC = __builtin_amdgcn_mfma_f32_16x16x32_bf16(a, bwL[ks], accC, 0, 0, 0);
    }

    bfrag8 bwP[4], bwT[4];
    #pragma unroll
    for (int ks = 0; ks < 4; ++ks) {
        bwP[ks] = *(const bfrag8*)((const char*)WP  + bcol * 256 + ks * 64 + koff2);
        bwT[ks] = *(const bfrag8*)((const char*)WT2 + bcol * 256 + ks * 64 + koff2);
    }

    float hid[4];
    #pragma unroll
    for (int q = 0; q < 4; ++q) {
        float o = accC[q] + biasC;
        hid[q] = 1.f / (1.f + __expf(-o));
        int row = (lane >> 4) * 4 + q;
        unsigned short hb = f2bf(hid[q]);
        *(unsigned short*)((char*)sH + row * 256 + ((bcol * 2) ^ ((row & 7) << 4))) = hb;
        hidb[(size_t)(n0 + row) * 64 + bcol] = hb;
    }

    __syncthreads();

    f4acc accP = {0.f, 0.f, 0.f, 0.f};
    f4acc accT = {0.f, 0.f, 0.f, 0.f};
    #pragma unroll
    for (int ks = 0; ks < 4; ++ks) {
        bfrag8 a = *(const bfrag8*)((const char*)sH + arow * 256 +
                                    ((ks * 64 + koff2) ^ ((arow & 7) << 4)));
        accP = __builtin_amdgcn_mfma_f32_16x16x32_bf16(a, bwP[ks], accP, 0, 0, 0);
        accT = __builtin_amdgcn_mfma_f32_16x16x32_bf16(a, bwT[ks], accT, 0, 0, 0);
    }

    #pragma unroll
    for (int q = 0; q < 4; ++q) {
        float proj = fmaxf(accP[q] + pbv, 0.f);
        float gate = 1.f / (1.f + __expf(-(accT[q] + tbv)));
        float o = gate * proj + (1.f - gate) * hid[q];
        int row = (lane >> 4) * 4 + q;
        if (last) outf[(size_t)(n0 + row) * 64 + bcol] = o;
        else      gatedb[(size_t)(n0 + row) * 64 + bcol] = f2bf(o);
    }
}

// ---------------------------------------------------------------------------
extern "C" void kernel_launch(void* const* d_in, const int* in_sizes, int n_in,
                              void* d_out, int out_size, void* d_ws, size_t ws_size,
                              hipStream_t stream)
{
    const float* node_feat = (const float*)d_in[0];
    const float* ew        = (const float*)d_in[1];
    const float* lin_w     = (const float*)d_in[2];
    const float* lin_b     = (const float*)d_in[3];
    const float* self_w    = (const float*)d_in[4];
    const float* self_b    = (const float*)d_in[5];
    const float* pw        = (const float*)d_in[6];
    const float* pb        = (const float*)d_in[7];
    const float* tw        = (const float*)d_in[8];
    const float* tb        = (const float*)d_in[9];
    const int*   src       = (const int*)d_in[10];
    const int*   dst       = (const int*)d_in[11];
    const int*   rel       = (const int*)d_in[12];
    float* outf = (float*)d_out;

    char* ws = (char*)d_ws;
    int*            row_ptr  = (int*)(ws + 0);            // (NB+1)*4
    int*            cnt_seg  = (int*)(ws + 1600256);      // NB*4
    int*            histBC   = (int*)(ws + 3200256);      // NHBC*4 = 400384
    int*            chunkOff = (int*)(ws + 3600640);      // NHBC*4
    int*            blksum   = (int*)(ws + 4001024);      // 512*4
    int*            blkoff   = (int*)(ws + 4003072);      // 512*4
    int2*           pA       = (int2*)(ws + 4005376);     // NE*8 = 12.8 MB
    int2*           edat     = (int2*)(ws + 16805376);    // (NE+32)*8
    unsigned short* nfb      = (unsigned short*)(ws + 29605632);
    unsigned short* hbfA     = (unsigned short*)(ws + 42405632);
    unsigned short* hbfB     = (unsigned short*)(ws + 55205632);
    unsigned short* gbfA     = (unsigned short*)(ws + 68005632);
    unsigned short* gbfB     = (unsigned short*)(ws + 80805632);
    unsigned short* WL       = (unsigned short*)(ws + 93605632);
    unsigned short* WP       = (unsigned short*)(ws + 93605632 + 122880);
    unsigned short* WT2      = (unsigned short*)(ws + 93605632 + 122880 + 49152);

    // ---- CSR build: deterministic two-phase counting sort ----
    hipMemsetAsync(cnt_seg, 0, NB * sizeof(int), stream);
    kA1<<<NCHK, 256, 0, stream>>>(dst, rel, cnt_seg, histBC);
    // segment scan (400K) -> row_ptr (+ total at row_ptr[NB])
    k_scan_local_g<<<391, 1024, 0, stream>>>(cnt_seg, row_ptr, blksum, NB);
    k_scan_blk_g<<<1, 512, 0, stream>>>(blksum, blkoff, 391, row_ptr + NB);
    k_scan_add_g<<<391, 1024, 0, stream>>>(row_ptr, blkoff, NB);
    // (bucket,chunk) scan (100096) -> chunkOff
    k_scan_local_g<<<98, 1024, 0, stream>>>(histBC, chunkOff, blksum, NHBC);
    k_scan_blk_g<<<1, 512, 0, stream>>>(blksum, blkoff, 98, (int*)nullptr);
    k_scan_add_g<<<98, 1024, 0, stream>>>(chunkOff, blkoff, NHBC);
    // partition + in-bucket sort
    kA3<<<NCHK, 256, 0, stream>>>(src, dst, rel, ew, chunkOff, pA);
    kB<<<NBUCK, 256, 0, stream>>>(row_ptr, pA, edat);

    // bf16 conversions
    k_cvt_x<<<25000, 256, 0, stream>>>(node_feat, nfb);
    k_cvt_w<<<432, 256, 0, stream>>>(lin_w, self_w, pw, tw, WL, WP, WT2);

    const unsigned short* cur  = nfb;
    const unsigned short* prev = nfb;
    unsigned short* hbuf[3] = { hbfA, hbfB, hbfA };
    unsigned short* gbuf[3] = { gbfA, gbfB, gbfA };

    for (int i = 0; i < 3; ++i) {
        int lastL = (i == 2);
        k_layer<<<NN / 16, 256, 0, stream>>>(
            cur, prev, row_ptr, edat,
            WL  + (size_t)i * 64 * 320,
            WP  + (size_t)i * 64 * 128,
            WT2 + (size_t)i * 64 * 128,
            lin_b + (size_t)i * 64, self_b + (size_t)i * 64,
            pb + (size_t)i * 64, tb + (size_t)i * 64,
            hbuf[i], gbuf[i], outf, lastL);
        cur  = gbuf[i];
        prev = hbuf[i];
    }
}

// Round 8
// 396.125 us; speedup vs baseline: 4.7988x; 1.1193x over previous
//
#include <hip/hip_runtime.h>

#define NN   100000
#define NE   1600000
#define NB   400000     // NN*4 (dst,rel) segments
#define EPS  1e-10f

#define NCHK  256       // edge chunks (phase A blocks)
#define EPC   6250      // NE / NCHK
#define NBUCK 391       // coarse buckets: dst>>8  (ceil(100000/256))
#define NHBC  (NBUCK * NCHK)   // 100096

typedef __attribute__((ext_vector_type(8))) short bfrag8;
typedef __attribute__((ext_vector_type(4))) float f4acc;

__device__ __forceinline__ unsigned short f2bf(float f) {
    union { float f; unsigned u; } v; v.f = f;
    unsigned r = v.u + 0x7FFF + ((v.u >> 16) & 1);
    return (unsigned short)(r >> 16);
}
__device__ __forceinline__ float bf2f(unsigned short b) {
    union { unsigned u; float f; } v; v.u = ((unsigned)b) << 16;
    return v.f;
}

// ---------------------------------------------------------------------------
// Phase A1: per-(bucket,chunk) histogram in LDS  +  400K segment histogram
// ---------------------------------------------------------------------------
__global__ __launch_bounds__(256) void kA1(
    const int* __restrict__ dst, const int* __restrict__ rel,
    int* __restrict__ cnt_seg, int* __restrict__ histBC)
{
    __shared__ int s_h[NBUCK];
    for (int i = threadIdx.x; i < NBUCK; i += 256) s_h[i] = 0;
    __syncthreads();
    int e0 = blockIdx.x * EPC;
    for (int e = e0 + threadIdx.x; e < e0 + EPC; e += 256) {
        int d = dst[e];
        atomicAdd(&s_h[d >> 8], 1);
        atomicAdd(&cnt_seg[d * 4 + rel[e]], 1);
    }
    __syncthreads();
    for (int i = threadIdx.x; i < NBUCK; i += 256)
        histBC[i * NCHK + blockIdx.x] = s_h[i];   // bucket-major
}

// --- generic coalesced 3-phase scan ----------------------------------------
__global__ __launch_bounds__(1024) void k_scan_local_g(
    const int* __restrict__ in, int* __restrict__ out,
    int* __restrict__ blksum, int n)
{
    __shared__ int s[1024];
    int t = threadIdx.x;
    int i = blockIdx.x * 1024 + t;
    int v = (i < n) ? in[i] : 0;
    s[t] = v;
    __syncthreads();
    #pragma unroll
    for (int off = 1; off < 1024; off <<= 1) {
        int u = (t >= off) ? s[t - off] : 0;
        __syncthreads();
        s[t] += u;
        __syncthreads();
    }
    if (i < n) out[i] = s[t] - v;
    if (t == 1023) blksum[blockIdx.x] = s[t];
}

__global__ __launch_bounds__(512) void k_scan_blk_g(
    int* __restrict__ blksum, int* __restrict__ blkoff,
    int nblk, int* __restrict__ total_dst)
{
    __shared__ int s[512];
    int t = threadIdx.x;
    int v = (t < nblk) ? blksum[t] : 0;
    s[t] = v;
    __syncthreads();
    #pragma unroll
    for (int off = 1; off < 512; off <<= 1) {
        int u = (t >= off) ? s[t - off] : 0;
        __syncthreads();
        s[t] += u;
        __syncthreads();
    }
    if (t < nblk) blkoff[t] = s[t] - v;
    if (total_dst && t == nblk - 1) *total_dst = s[t];
}

__global__ __launch_bounds__(1024) void k_scan_add_g(
    int* __restrict__ out, const int* __restrict__ blkoff, int n)
{
    int i = blockIdx.x * 1024 + threadIdx.x;
    if (i < n) out[i] += blkoff[blockIdx.x];
}

// ---------------------------------------------------------------------------
// Phase A3: partition edges into coarse buckets (line-dense writes).
// ---------------------------------------------------------------------------
__global__ __launch_bounds__(256) void kA3(
    const int* __restrict__ src, const int* __restrict__ dst,
    const int* __restrict__ rel, const float* __restrict__ ew,
    const int* __restrict__ chunkOff, int2* __restrict__ pA)
{
    __shared__ int s_c[NBUCK];
    for (int i = threadIdx.x; i < NBUCK; i += 256)
        s_c[i] = chunkOff[i * NCHK + blockIdx.x];
    __syncthreads();
    int e0 = blockIdx.x * EPC;
    for (int e = e0 + threadIdx.x; e < e0 + EPC; e += 256) {
        int d = dst[e], r = rel[e];
        int pos = atomicAdd(&s_c[d >> 8], 1);
        int2 v;
        v.x = src[e] | (((d & 255) * 4 + r) << 20);
        v.y = __float_as_int(ew[e]);
        pA[pos] = v;
    }
}

// ---------------------------------------------------------------------------
// Phase B: one block per bucket; in-bucket counting sort by seg_local.
// ---------------------------------------------------------------------------
__global__ __launch_bounds__(256) void kB(
    const int* __restrict__ row_ptr, const int2* __restrict__ pA,
    int2* __restrict__ edat)
{
    __shared__ int s_c[1024];
    __shared__ int s_p[256];
    const int b    = blockIdx.x;
    const int t    = threadIdx.x;
    const int seg0 = b * 1024;
    const int segN = min(1024, NB - seg0);
    const int pbeg = row_ptr[seg0];
    const int pend = row_ptr[seg0 + segN];

    for (int i = t; i < 1024; i += 256) s_c[i] = 0;
    __syncthreads();
    for (int p = pbeg + t; p < pend; p += 256)
        atomicAdd(&s_c[((unsigned)pA[p].x) >> 20], 1);
    __syncthreads();

    int c0 = s_c[t * 4], c1 = s_c[t * 4 + 1], c2 = s_c[t * 4 + 2], c3 = s_c[t * 4 + 3];
    int tsum = c0 + c1 + c2 + c3;
    s_p[t] = tsum;
    __syncthreads();
    #pragma unroll
    for (int off = 1; off < 256; off <<= 1) {
        int u = (t >= off) ? s_p[t - off] : 0;
        __syncthreads();
        s_p[t] += u;
        __syncthreads();
    }
    int base = s_p[t] - tsum;
    s_c[t * 4]     = base;
    s_c[t * 4 + 1] = base + c0;
    s_c[t * 4 + 2] = base + c0 + c1;
    s_c[t * 4 + 3] = base + c0 + c1 + c2;
    __syncthreads();

    for (int p = pbeg + t; p < pend; p += 256) {
        int2 v = pA[p];
        int sl = ((unsigned)v.x) >> 20;
        int pos = atomicAdd(&s_c[sl], 1);
        int2 o; o.x = v.x & 0xFFFFF; o.y = v.y;
        edat[pbeg + pos] = o;
    }
    // 128 zero pad entries: layer kernel over-reads meta up to NE+127
    if (b == 0 && t < 128) { int2 z; z.x = 0; z.y = 0; edat[NE + t] = z; }
}

// ---------------------------------------------------------------------------
// Conversions
// ---------------------------------------------------------------------------
__global__ __launch_bounds__(256) void k_cvt_x(
    const float* __restrict__ xf, unsigned short* __restrict__ xb)
{
    int i = blockIdx.x * 256 + threadIdx.x;
    if (i < NN * 64) xb[i] = f2bf(xf[i]);
}

__global__ __launch_bounds__(256) void k_cvt_w(
    const float* __restrict__ lin_w, const float* __restrict__ self_w,
    const float* __restrict__ pw, const float* __restrict__ tw,
    unsigned short* __restrict__ WL, unsigned short* __restrict__ WP,
    unsigned short* __restrict__ WT2)
{
    int id = blockIdx.x * 256 + threadIdx.x;   // 3*64*576
    if (id >= 3 * 64 * 576) return;
    int i = id / (64 * 576);
    int r = id % (64 * 576);
    int j = r / 576;
    int k = r % 576;
    if (k < 320) {
        float v = (k < 256) ? lin_w[((size_t)i * 256 + k) * 64 + j]
                            : self_w[((size_t)i * 64 + (k - 256)) * 64 + j];
        WL[((size_t)i * 64 + j) * 320 + k] = f2bf(v);
    } else if (k < 448) {
        int kk = k - 320;
        WP[((size_t)i * 64 + j) * 128 + kk] = f2bf(pw[((size_t)i * 128 + kk) * 64 + j]);
    } else {
        int kk = k - 448;
        WT2[((size_t)i * 64 + j) * 128 + kk] = f2bf(tw[((size_t)i * 128 + kk) * 64 + j]);
    }
}

// ---------------------------------------------------------------------------
// Scalarized edge-stream helpers for k_layer.
// Meta for 64 edges lives in one per-lane int2 (lane j = edge base+j);
// per-edge src/w broadcast via readlane (literal index, SGPR result).
// ---------------------------------------------------------------------------
template<int LBASE>
__device__ __forceinline__ void gather16(
    unsigned short (&g)[16], int2 mb,
    const unsigned short* __restrict__ xb, int lane)
{
    #pragma unroll
    for (int j = 0; j < 16; ++j) {
        unsigned sm = (unsigned)__builtin_amdgcn_readlane(mb.x, LBASE + j);
        g[j] = xb[((size_t)sm << 6) + lane];
    }
}

template<int LBASE>
__device__ __forceinline__ void consume16(
    const unsigned short (&g)[16], int2 mb, int ebase,
    int E1, int& seg, int& segEnd,
    float& acc, float& dsum,
    const int* sRP, int sbase, int wid, int lane, char* sAp)
{
    #pragma unroll
    for (int j = 0; j < 16; ++j) {
        int eidx = ebase + j;                          // scalar
        if (eidx < E1) {                               // s_cmp path
            while (eidx >= segEnd) {                   // flush finished segments
                float u = acc / (dsum + EPS);
                int ln = wid * 4 + (seg >> 2);
                int cb = ((seg & 3) * 64 + lane) * 2;
                *(unsigned short*)(sAp + ln * 640 + (cb ^ ((ln & 7) << 4))) = f2bf(u);
                acc = 0.f; dsum = 0.f;
                ++seg;
                segEnd = __builtin_amdgcn_readfirstlane(sRP[sbase + seg + 1]);
            }
            float w = __int_as_float(__builtin_amdgcn_readlane(mb.y, LBASE + j));
            acc = fmaf(bf2f(g[j]), w, acc);
            dsum += w;
        }
    }
}

// ---------------------------------------------------------------------------
// Fused layer: scalarized depth-16 pipelined edge-aggregate -> conv MFMA
// -> sigmoid -> highway MFMA -> gated. 256 threads = 4 waves, 16 nodes.
// ---------------------------------------------------------------------------
__global__ __launch_bounds__(256, 4) void k_layer(
    const unsigned short* __restrict__ xb,     // layer input bf16 [NN][64]
    const unsigned short* __restrict__ prevb,  // prev hidden bf16 [NN][64]
    const int* __restrict__ row_ptr,
    const int2* __restrict__ edat,
    const unsigned short* __restrict__ WL,     // [64][320]
    const unsigned short* __restrict__ WP,     // [64][128]
    const unsigned short* __restrict__ WT2,    // [64][128]
    const float* __restrict__ lin_b, const float* __restrict__ self_b,
    const float* __restrict__ pb, const float* __restrict__ tb,
    unsigned short* __restrict__ hidb,
    unsigned short* __restrict__ gatedb,
    float* __restrict__ outf,
    int last)
{
    __shared__ __align__(16) unsigned short sA[16 * 320];  // 10240 B
    __shared__ __align__(16) unsigned short sH[16 * 128];  //  4096 B
    __shared__ int sRP[65];

    const int tid  = threadIdx.x;
    const int lane = tid & 63;
    const int wid  = tid >> 6;
    const int n0   = blockIdx.x * 16;
    const int bcol = wid * 16 + (lane & 15);
    const int koff2 = (lane >> 4) * 16;
    const int arow = lane & 15;

    if (tid < 65) sRP[tid] = row_ptr[n0 * 4 + tid];

    #pragma unroll
    for (int j = 0; j < 4; ++j) {
        int idx = tid + 256 * j;
        int row = idx >> 6, col = idx & 63;
        int cb = (64 + col) * 2;
        *(unsigned short*)((char*)sH + row * 256 + (cb ^ ((row & 7) << 4))) =
            prevb[(size_t)(n0 + row) * 64 + col];
    }
    #pragma unroll
    for (int j = 0; j < 4; ++j) {
        int ln = wid * 4 + j;
        int cb = (256 + lane) * 2;
        *(unsigned short*)((char*)sA + ln * 640 + (cb ^ ((ln & 7) << 4))) =
            xb[(size_t)(n0 + ln) * 64 + lane];
    }

    __syncthreads();

    // ---- scalarized edge aggregation over the wave's 16 segments ----
    const int sbase = wid * 16;
    int E0 = __builtin_amdgcn_readfirstlane(sRP[sbase]);
    int E1 = __builtin_amdgcn_readfirstlane(sRP[sbase + 16]);
    int seg = 0;
    int segEnd = __builtin_amdgcn_readfirstlane(sRP[sbase + 1]);
    float acc = 0.f, dsum = 0.f;

    int2 mb = edat[E0 + lane];       // meta for edges E0..E0+63 (lane j = edge j)
    unsigned short ga[16], gb[16];
    gather16<0>(ga, mb, xb, lane);

    for (int e = E0; e < E1; e += 64) {
        int2 mbn = edat[e + 64 + lane];              // next meta block (padded)
        gather16<16>(gb, mb, xb, lane);
        consume16<0>(ga, mb, e, E1, seg, segEnd, acc, dsum, sRP, sbase, wid, lane, (char*)sA);
        gather16<32>(ga, mb, xb, lane);
        consume16<16>(gb, mb, e + 16, E1, seg, segEnd, acc, dsum, sRP, sbase, wid, lane, (char*)sA);
        gather16<48>(gb, mb, xb, lane);
        consume16<32>(ga, mb, e + 32, E1, seg, segEnd, acc, dsum, sRP, sbase, wid, lane, (char*)sA);
        gather16<0>(ga, mbn, xb, lane);
        consume16<48>(gb, mb, e + 48, E1, seg, segEnd, acc, dsum, sRP, sbase, wid, lane, (char*)sA);
        mb = mbn;
    }
    while (seg < 16) {                               // trailing flush
        float u = acc / (dsum + EPS);
        int ln = wid * 4 + (seg >> 2);
        int cb = ((seg & 3) * 64 + lane) * 2;
        *(unsigned short*)((char*)sA + ln * 640 + (cb ^ ((ln & 7) << 4))) = f2bf(u);
        acc = 0.f; dsum = 0.f;
        ++seg;
    }

    bfrag8 bwL[10];
    #pragma unroll
    for (int ks = 0; ks < 10; ++ks)
        bwL[ks] = *(const bfrag8*)((const char*)WL + bcol * 640 + ks * 64 + koff2);
    float biasC = lin_b[bcol] + self_b[bcol];
    float pbv = pb[bcol], tbv = tb[bcol];

    __syncthreads();

    f4acc accC = {0.f, 0.f, 0.f, 0.f};
    #pragma unroll
    for (int ks = 0; ks < 10; ++ks) {
        bfrag8 a = *(const bfrag8*)((const char*)sA + arow * 640 +
                                    ((ks * 64 + koff2) ^ ((arow & 7) << 4)));
        accC = __builtin_amdgcn_mfma_f32_16x16x32_bf16(a, bwL[ks], accC, 0, 0, 0);
    }

    bfrag8 bwP[4], bwT[4];
    #pragma unroll
    for (int ks = 0; ks < 4; ++ks) {
        bwP[ks] = *(const bfrag8*)((const char*)WP  + bcol * 256 + ks * 64 + koff2);
        bwT[ks] = *(const bfrag8*)((const char*)WT2 + bcol * 256 + ks * 64 + koff2);
    }

    float hid[4];
    #pragma unroll
    for (int q = 0; q < 4; ++q) {
        float o = accC[q] + biasC;
        hid[q] = 1.f / (1.f + __expf(-o));
        int row = (lane >> 4) * 4 + q;
        unsigned short hb = f2bf(hid[q]);
        *(unsigned short*)((char*)sH + row * 256 + ((bcol * 2) ^ ((row & 7) << 4))) = hb;
        hidb[(size_t)(n0 + row) * 64 + bcol] = hb;
    }

    __syncthreads();

    f4acc accP = {0.f, 0.f, 0.f, 0.f};
    f4acc accT = {0.f, 0.f, 0.f, 0.f};
    #pragma unroll
    for (int ks = 0; ks < 4; ++ks) {
        bfrag8 a = *(const bfrag8*)((const char*)sH + arow * 256 +
                                    ((ks * 64 + koff2) ^ ((arow & 7) << 4)));
        accP = __builtin_amdgcn_mfma_f32_16x16x32_bf16(a, bwP[ks], accP, 0, 0, 0);
        accT = __builtin_amdgcn_mfma_f32_16x16x32_bf16(a, bwT[ks], accT, 0, 0, 0);
    }

    #pragma unroll
    for (int q = 0; q < 4; ++q) {
        float proj = fmaxf(accP[q] + pbv, 0.f);
        float gate = 1.f / (1.f + __expf(-(accT[q] + tbv)));
        float o = gate * proj + (1.f - gate) * hid[q];
        int row = (lane >> 4) * 4 + q;
        if (last) outf[(size_t)(n0 + row) * 64 + bcol] = o;
        else      gatedb[(size_t)(n0 + row) * 64 + bcol] = f2bf(o);
    }
}

// ---------------------------------------------------------------------------
extern "C" void kernel_launch(void* const* d_in, const int* in_sizes, int n_in,
                              void* d_out, int out_size, void* d_ws, size_t ws_size,
                              hipStream_t stream)
{
    const float* node_feat = (const float*)d_in[0];
    const float* ew        = (const float*)d_in[1];
    const float* lin_w     = (const float*)d_in[2];
    const float* lin_b     = (const float*)d_in[3];
    const float* self_w    = (const float*)d_in[4];
    const float* self_b    = (const float*)d_in[5];
    const float* pw        = (const float*)d_in[6];
    const float* pb        = (const float*)d_in[7];
    const float* tw        = (const float*)d_in[8];
    const float* tb        = (const float*)d_in[9];
    const int*   src       = (const int*)d_in[10];
    const int*   dst       = (const int*)d_in[11];
    const int*   rel       = (const int*)d_in[12];
    float* outf = (float*)d_out;

    char* ws = (char*)d_ws;
    int*            row_ptr  = (int*)(ws + 0);            // (NB+1)*4
    int*            cnt_seg  = (int*)(ws + 1600256);      // NB*4
    int*            histBC   = (int*)(ws + 3200256);      // NHBC*4
    int*            chunkOff = (int*)(ws + 3600640);      // NHBC*4
    int*            blksum   = (int*)(ws + 4001024);
    int*            blkoff   = (int*)(ws + 4003072);
    int2*           pA       = (int2*)(ws + 4005376);     // NE*8
    int2*           edat     = (int2*)(ws + 16805376);    // (NE+128)*8
    unsigned short* nfb      = (unsigned short*)(ws + 29606400);
    unsigned short* hbfA     = (unsigned short*)(ws + 42406400);
    unsigned short* hbfB     = (unsigned short*)(ws + 55206400);
    unsigned short* gbfA     = (unsigned short*)(ws + 68006400);
    unsigned short* gbfB     = (unsigned short*)(ws + 80806400);
    unsigned short* WL       = (unsigned short*)(ws + 93606400);
    unsigned short* WP       = (unsigned short*)(ws + 93606400 + 122880);
    unsigned short* WT2      = (unsigned short*)(ws + 93606400 + 122880 + 49152);

    // ---- CSR build: deterministic two-phase counting sort ----
    hipMemsetAsync(cnt_seg, 0, NB * sizeof(int), stream);
    kA1<<<NCHK, 256, 0, stream>>>(dst, rel, cnt_seg, histBC);
    k_scan_local_g<<<391, 1024, 0, stream>>>(cnt_seg, row_ptr, blksum, NB);
    k_scan_blk_g<<<1, 512, 0, stream>>>(blksum, blkoff, 391, row_ptr + NB);
    k_scan_add_g<<<391, 1024, 0, stream>>>(row_ptr, blkoff, NB);
    k_scan_local_g<<<98, 1024, 0, stream>>>(histBC, chunkOff, blksum, NHBC);
    k_scan_blk_g<<<1, 512, 0, stream>>>(blksum, blkoff, 98, (int*)nullptr);
    k_scan_add_g<<<98, 1024, 0, stream>>>(chunkOff, blkoff, NHBC);
    kA3<<<NCHK, 256, 0, stream>>>(src, dst, rel, ew, chunkOff, pA);
    kB<<<NBUCK, 256, 0, stream>>>(row_ptr, pA, edat);

    // bf16 conversions
    k_cvt_x<<<25000, 256, 0, stream>>>(node_feat, nfb);
    k_cvt_w<<<432, 256, 0, stream>>>(lin_w, self_w, pw, tw, WL, WP, WT2);

    const unsigned short* cur  = nfb;
    const unsigned short* prev = nfb;
    unsigned short* hbuf[3] = { hbfA, hbfB, hbfA };
    unsigned short* gbuf[3] = { gbfA, gbfB, gbfA };

    for (int i = 0; i < 3; ++i) {
        int lastL = (i == 2);
        k_layer<<<NN / 16, 256, 0, stream>>>(
            cur, prev, row_ptr, edat,
            WL  + (size_t)i * 64 * 320,
            WP  + (size_t)i * 64 * 128,
            WT2 + (size_t)i * 64 * 128,
            lin_b + (size_t)i * 64, self_b + (size_t)i * 64,
            pb + (size_t)i * 64, tb + (size_t)i * 64,
            hbuf[i], gbuf[i], outf, lastL);
        cur  = gbuf[i];
        prev = hbuf[i];
    }
}